// Round 1
// baseline (49.858 us; speedup 1.0000x reference)
//
#include <hip/hip_runtime.h>
#include <math.h>

// out[r, v] = sin(x[r] * freqs[v]),  r in [0, 64*4096), v in [0, 256)
// freqs[v] = 10^(min(v,127)/127 * 4)
//
// Strategy: one wave (64 lanes) per row; lane l covers v = 4l..4l+3 and does a
// single float4 store (64 lanes * 16 B = 1024 B contiguous per row).
// sin computed via hardware v_sin_f32 (revolution input): precompute
// c[v] = freqs[v]/(2*pi) in f64 once per thread, then per element it's just
// v_mul + v_fract + v_sin.

__global__ __launch_bounds__(256) void InputLayer_57337813401914_kernel(
    const float* __restrict__ x, float* __restrict__ out, int rows) {
  const int lane = threadIdx.x & 63;
  const int gwave = (int)((blockIdx.x * blockDim.x + threadIdx.x) >> 6);
  const int nwaves = (int)((gridDim.x * blockDim.x) >> 6);

  // Per-thread frequency constants (freq / 2pi), computed once in f64.
  float c[4];
#pragma unroll
  for (int j = 0; j < 4; ++j) {
    int v = 4 * lane + j;
    int idx = v < 128 ? v : 127;
    double e = (double)idx * (4.0 / 127.0);
    double f = pow(10.0, e);
    c[j] = (float)(f * 0.15915494309189535);  // f / (2*pi)
  }

  for (int r = gwave; r < rows; r += nwaves) {
    float xv = x[r];  // all 64 lanes read same address -> broadcast from L1
    float4 o;
    float r0 = __builtin_amdgcn_fractf(xv * c[0]);
    float r1 = __builtin_amdgcn_fractf(xv * c[1]);
    float r2 = __builtin_amdgcn_fractf(xv * c[2]);
    float r3 = __builtin_amdgcn_fractf(xv * c[3]);
    o.x = __builtin_amdgcn_sinf(r0);
    o.y = __builtin_amdgcn_sinf(r1);
    o.z = __builtin_amdgcn_sinf(r2);
    o.w = __builtin_amdgcn_sinf(r3);
    *reinterpret_cast<float4*>(out + (size_t)r * 256 + (size_t)lane * 4) = o;
  }
}

extern "C" void kernel_launch(void* const* d_in, const int* in_sizes, int n_in,
                              void* d_out, int out_size, void* d_ws, size_t ws_size,
                              hipStream_t stream) {
  const float* x = (const float*)d_in[0];
  float* out = (float*)d_out;
  const int rows = in_sizes[0];  // 64 * 4096 = 262144

  const int block = 256;
  const int grid = 2048;  // 8 blocks/CU on 256 CUs; grid-stride over rows
  InputLayer_57337813401914_kernel<<<grid, block, 0, stream>>>(x, out, rows);
}